// Round 1
// baseline (44.504 us; speedup 1.0000x reference)
//
#include <hip/hip_runtime.h>

// DynamicMaskHead: 128 instances, crop 96x128 from (2,8,192,256) feats,
// per-instance MLP 10->8->8->1 (relu,relu,linear), bilinear 2x upsample
// to 192x256, sigmoid.
//
// Grid: 512 blocks = 128 instances x 4 row-quarters. 256 threads/block.
// Phase 1: compute 26 mask rows (pre-sigmoid) into LDS.
// Phase 2: upsample 48 output rows x 256 cols, sigmoid, coalesced store.

#define HH 192
#define WW 256
#define IH 96
#define IW 128

__global__ __launch_bounds__(256, 2) void dmh_kernel(
    const float* __restrict__ mf,      // (2,8,192,256)
    const float* __restrict__ params,  // (128,169)
    const float* __restrict__ locs,    // (128,2)
    const int*   __restrict__ im_inds, // (128)
    const int*   __restrict__ fpn,     // (128)
    const int*   __restrict__ stride_p,// (1)
    float*       __restrict__ out)     // (128,1,192,256)
{
    __shared__ float m[26 * IW];       // 13 KB mask-row stage

    const int bx   = blockIdx.x;
    const int inst = bx >> 2;
    const int q    = bx & 3;
    const int tid  = threadIdx.x;

    const int   s   = stride_p[0];      // 8
    const int   sh  = s >> 1;           // 4
    const float ix  = locs[2 * inst + 0];
    const float iy  = locs[2 * inst + 1];
    const int   lvl = fpn[inst];
    const float inv_soi = 1.0f / (float)(64 << lvl);   // SOI are powers of 2
    const int   im  = im_inds[inst];

    // grid-cell selection (matches jnp: clip then true f32 divide, floor)
    const float nlx = ix * 0.125f;
    const float nly = iy * 0.125f;
    const int gx = (int)floorf(fminf(fmaxf(nlx, 0.0f), (float)(WW - 1)) / (float)(WW / 2));
    const int gy = (int)floorf(fminf(fmaxf(nly, 0.0f), (float)(HH - 1)) / (float)(HH / 2));

    const float* __restrict__ p = params + inst * 169;

    // mask-row window start for this quarter: {0,23,47,71}
    const int ms = (q * 95) >> 2;

    // ---------------- Phase 1: mask rows [ms, ms+25] into LDS ----------------
    {
        const int col   = tid & (IW - 1);
        const int r0    = tid >> 7;            // 0 or 1
        const int wglob = gx * IW + col;
        const float sxf  = (float)(wglob * s + sh);
        const float relx = (ix - sxf) * inv_soi;

        #pragma unroll
        for (int i = 0; i < 13; ++i) {
            const int r  = r0 + 2 * i;         // 0..25
            const int gr = ms + r;             // block-local mask row
            if (gr < IH) {
                const int h = gy * IH + gr;    // global feature row
                const float syf  = (float)(h * s + sh);
                const float rely = (iy - syf) * inv_soi;

                const float* fp = mf + ((size_t)(im * 8) * HH + h) * WW + wglob;
                float f[8];
                #pragma unroll
                for (int c = 0; c < 8; ++c) f[c] = fp[(size_t)c * HH * WW];

                // layer 0: 10 -> 8, relu
                float a[8];
                #pragma unroll
                for (int k = 0; k < 8; ++k) {
                    float acc = p[152 + k];
                    acc = fmaf(p[k * 10 + 0], relx, acc);
                    acc = fmaf(p[k * 10 + 1], rely, acc);
                    #pragma unroll
                    for (int c = 0; c < 8; ++c)
                        acc = fmaf(p[k * 10 + 2 + c], f[c], acc);
                    a[k] = fmaxf(acc, 0.0f);
                }
                // layer 1: 8 -> 8, relu
                float b[8];
                #pragma unroll
                for (int k = 0; k < 8; ++k) {
                    float acc = p[160 + k];
                    #pragma unroll
                    for (int c = 0; c < 8; ++c)
                        acc = fmaf(p[80 + k * 8 + c], a[c], acc);
                    b[k] = fmaxf(acc, 0.0f);
                }
                // layer 2: 8 -> 1
                float acc = p[168];
                #pragma unroll
                for (int c = 0; c < 8; ++c)
                    acc = fmaf(p[144 + c], b[c], acc);

                m[r * IW + col] = acc;
            }
        }
    }
    __syncthreads();

    // ---------------- Phase 2: upsample 48 rows x 256 cols, sigmoid ----------
    {
        const int ocol = tid;                                // 0..255
        const float wpos = (float)ocol * (127.0f / 255.0f);
        int wlo = (int)wpos;  if (wlo > IW - 2) wlo = IW - 2;
        const float fw = wpos - (float)wlo;

        float* orow = out + (size_t)inst * (HH * WW) + (size_t)q * 48 * WW + ocol;

        #pragma unroll 4
        for (int r = 0; r < 48; ++r) {
            const int grow = q * 48 + r;
            const float hpos = (float)grow * (95.0f / 191.0f);
            int hlo = (int)hpos;  if (hlo > IH - 2) hlo = IH - 2;
            const float fh = hpos - (float)hlo;
            const int rl = hlo - ms;

            const float v00 = m[rl * IW + wlo];
            const float v01 = m[rl * IW + wlo + 1];
            const float v10 = m[(rl + 1) * IW + wlo];
            const float v11 = m[(rl + 1) * IW + wlo + 1];

            const float top = (1.0f - fw) * v00 + fw * v01;
            const float bot = (1.0f - fw) * v10 + fw * v11;
            const float v   = (1.0f - fh) * top + fh * bot;

            orow[(size_t)r * WW] = 1.0f / (1.0f + __expf(-v));
        }
    }
}

extern "C" void kernel_launch(void* const* d_in, const int* in_sizes, int n_in,
                              void* d_out, int out_size, void* d_ws, size_t ws_size,
                              hipStream_t stream) {
    const float* mf       = (const float*)d_in[0];
    const float* params   = (const float*)d_in[1];
    const float* locs     = (const float*)d_in[2];
    const int*   im_inds  = (const int*)d_in[3];
    const int*   fpn      = (const int*)d_in[4];
    const int*   stride_p = (const int*)d_in[5];
    float*       out      = (float*)d_out;

    dmh_kernel<<<dim3(512), dim3(256), 0, stream>>>(
        mf, params, locs, im_inds, fpn, stride_p, out);
}

// Round 2
// 25.459 us; speedup vs baseline: 1.7480x; 1.7480x over previous
//
#include <hip/hip_runtime.h>

// DynamicMaskHead: 128 instances, crop 96x128 from (2,8,192,256) feats,
// per-instance MLP 10->8->8->1 (relu,relu,linear), bilinear 2x upsample
// to 192x256, sigmoid.
//
// Grid: 2048 blocks = 128 instances x 16 row-slices. 256 threads/block.
// Phase 1: compute 8 mask rows (pre-sigmoid) into LDS (4 KB), with manual
//          double-buffered feature loads (2 rows in flight).
// Phase 2: upsample 12 output rows x 256 cols, sigmoid, float4 stores.

#define HH 192
#define WW 256
#define IH 96
#define IW 128
#define HW (HH * WW)

__global__ __launch_bounds__(256, 8) void dmh_kernel(
    const float* __restrict__ mf,      // (2,8,192,256)
    const float* __restrict__ params,  // (128,169)
    const float* __restrict__ locs,    // (128,2)
    const int*   __restrict__ im_inds, // (128)
    const int*   __restrict__ fpn,     // (128)
    const int*   __restrict__ stride_p,// (1)
    float*       __restrict__ out)     // (128,1,192,256)
{
    __shared__ float m[8 * IW];        // 4 KB mask-row stage

    const int bx   = blockIdx.x;
    const int inst = bx >> 4;
    const int q    = bx & 15;
    const int tid  = threadIdx.x;

    const int   s   = stride_p[0];     // 8
    const int   sh  = s >> 1;          // 4
    const float ix  = locs[2 * inst + 0];
    const float iy  = locs[2 * inst + 1];
    const float inv_soi = 1.0f / (float)(64 << fpn[inst]); // SOI are pow2
    const int   im  = im_inds[inst];

    // grid-cell selection (matches jnp: clip then true f32 divide, floor)
    const float nlx = ix * 0.125f;
    const float nly = iy * 0.125f;
    const int gx = (int)floorf(fminf(fmaxf(nlx, 0.0f), (float)(WW - 1)) / (float)(WW / 2));
    const int gy = (int)floorf(fminf(fmaxf(nly, 0.0f), (float)(HH - 1)) / (float)(HH / 2));

    const float* __restrict__ p = params + inst * 169;

    const int orow0 = q * 12;                                // first output row
    const int ms    = (int)((float)orow0 * (95.0f / 191.0f)); // first mask row

    // ---------------- Phase 1: mask rows [ms, ms+7] into LDS ----------------
    {
        const int col   = tid & (IW - 1);
        const int r0    = tid >> 7;            // 0 or 1
        const int wglob = gx * IW + col;
        const float relx = (ix - (float)(wglob * s + sh)) * inv_soi;
        const float* __restrict__ base = mf + (size_t)(im * 8) * HW + wglob;

        auto LOAD = [&](int r, float* f, float& rely) {
            int gr = ms + r; if (gr > IH - 1) gr = IH - 1;   // clamp (row unused)
            const int h = gy * IH + gr;
            rely = (iy - (float)(h * s + sh)) * inv_soi;
            const float* fp = base + (size_t)h * WW;
            #pragma unroll
            for (int c = 0; c < 8; ++c) f[c] = fp[(size_t)c * HW];
        };
        auto MLP = [&](const float* f, float rely) -> float {
            float a[8];
            #pragma unroll
            for (int k = 0; k < 8; ++k) {
                float acc = p[152 + k];
                acc = fmaf(p[k * 10 + 0], relx, acc);
                acc = fmaf(p[k * 10 + 1], rely, acc);
                #pragma unroll
                for (int c = 0; c < 8; ++c)
                    acc = fmaf(p[k * 10 + 2 + c], f[c], acc);
                a[k] = fmaxf(acc, 0.0f);
            }
            float b[8];
            #pragma unroll
            for (int k = 0; k < 8; ++k) {
                float acc = p[160 + k];
                #pragma unroll
                for (int c = 0; c < 8; ++c)
                    acc = fmaf(p[80 + k * 8 + c], a[c], acc);
                b[k] = fmaxf(acc, 0.0f);
            }
            float acc = p[168];
            #pragma unroll
            for (int c = 0; c < 8; ++c)
                acc = fmaf(p[144 + c], b[c], acc);
            return acc;
        };

        // rows r0, r0+2, r0+4, r0+6 — manual 2-deep pipeline
        float fA[8], fB[8], ryA, ryB;
        LOAD(r0,     fA, ryA);
        LOAD(r0 + 2, fB, ryB);
        m[(r0    ) * IW + col] = MLP(fA, ryA);
        LOAD(r0 + 4, fA, ryA);
        m[(r0 + 2) * IW + col] = MLP(fB, ryB);
        LOAD(r0 + 6, fB, ryB);
        m[(r0 + 4) * IW + col] = MLP(fA, ryA);
        m[(r0 + 6) * IW + col] = MLP(fB, ryB);
    }
    __syncthreads();

    // ---------------- Phase 2: upsample 12 rows x 256 cols, float4 stores ---
    {
        const int c0    = (tid & 63) * 4;      // column base (lane*4)
        const int rbase = tid >> 6;            // 0..3 (one row per wave)

        float fw[4]; int wlo[4];
        #pragma unroll
        for (int j = 0; j < 4; ++j) {
            const float wpos = (float)(c0 + j) * (127.0f / 255.0f);
            int l = (int)wpos; if (l > IW - 2) l = IW - 2;
            wlo[j] = l; fw[j] = wpos - (float)l;
        }

        float* obase = out + (size_t)inst * HW + (size_t)orow0 * WW + c0;

        #pragma unroll
        for (int i = 0; i < 3; ++i) {
            const int r = rbase + i * 4;       // 0..11
            const float hpos = (float)(orow0 + r) * (95.0f / 191.0f);
            int hlo = (int)hpos; if (hlo > IH - 2) hlo = IH - 2;
            const float fh = hpos - (float)hlo;
            const int rl = hlo - ms;           // 0..5

            float4 v;
            float* vv = &v.x;
            #pragma unroll
            for (int j = 0; j < 4; ++j) {
                const float v00 = m[rl * IW + wlo[j]];
                const float v01 = m[rl * IW + wlo[j] + 1];
                const float v10 = m[(rl + 1) * IW + wlo[j]];
                const float v11 = m[(rl + 1) * IW + wlo[j] + 1];
                const float top = fmaf(fw[j], v01 - v00, v00);
                const float bot = fmaf(fw[j], v11 - v10, v10);
                const float val = fmaf(fh, bot - top, top);
                vv[j] = 1.0f / (1.0f + __expf(-val));
            }
            *(float4*)(obase + (size_t)r * WW) = v;
        }
    }
}

extern "C" void kernel_launch(void* const* d_in, const int* in_sizes, int n_in,
                              void* d_out, int out_size, void* d_ws, size_t ws_size,
                              hipStream_t stream) {
    const float* mf       = (const float*)d_in[0];
    const float* params   = (const float*)d_in[1];
    const float* locs     = (const float*)d_in[2];
    const int*   im_inds  = (const int*)d_in[3];
    const int*   fpn      = (const int*)d_in[4];
    const int*   stride_p = (const int*)d_in[5];
    float*       out      = (float*)d_out;

    dmh_kernel<<<dim3(2048), dim3(256), 0, stream>>>(
        mf, params, locs, im_inds, fpn, stride_p, out);
}

// Round 3
// 20.574 us; speedup vs baseline: 2.1631x; 1.2374x over previous
//
#include <hip/hip_runtime.h>

// DynamicMaskHead: 128 instances, crop 96x128 from (2,8,192,256) feats,
// per-instance MLP 10->8->8->1 (relu,relu,linear), bilinear 2x upsample
// to 192x256, sigmoid.
//
// Grid: 2048 blocks = 128 instances x 16 row-slices. 256 threads/block.
// Phase 1: 8 mask rows into LDS; thread = (row, 4 cols), float4 feat loads.
// Phase 2: thread = 1 output col x 12 rows; 2x ds_read2_b32 per row,
//          conflict-free (consecutive-dword lanes), coalesced dword stores.

#define HH 192
#define WW 256
#define IH 96
#define IW 128
#define HW (HH * WW)

__global__ __launch_bounds__(256, 6) void dmh_kernel(
    const float* __restrict__ mf,      // (2,8,192,256)
    const float* __restrict__ params,  // (128,169)
    const float* __restrict__ locs,    // (128,2)
    const int*   __restrict__ im_inds, // (128)
    const int*   __restrict__ fpn,     // (128)
    const int*   __restrict__ stride_p,// (1)
    float*       __restrict__ out)     // (128,1,192,256)
{
    __shared__ float m[8 * IW];        // 4 KB mask-row stage

    const int bx   = blockIdx.x;
    const int inst = bx >> 4;
    const int q    = bx & 15;
    const int tid  = threadIdx.x;

    const int   s   = stride_p[0];     // 8
    const int   sh  = s >> 1;          // 4
    const float ix  = locs[2 * inst + 0];
    const float iy  = locs[2 * inst + 1];
    const float inv_soi = 1.0f / (float)(64 << fpn[inst]); // SOI are pow2
    const int   im  = im_inds[inst];

    // grid-cell selection (matches jnp: clip then true f32 divide, floor)
    const float nlx = ix * 0.125f;
    const float nly = iy * 0.125f;
    const int gx = (int)floorf(fminf(fmaxf(nlx, 0.0f), (float)(WW - 1)) / (float)(WW / 2));
    const int gy = (int)floorf(fminf(fmaxf(nly, 0.0f), (float)(HH - 1)) / (float)(HH / 2));

    const float* __restrict__ p = params + inst * 169;

    const int orow0 = q * 12;                                 // first output row
    const int ms    = (int)((float)orow0 * (95.0f / 191.0f)); // first mask row

    // ------- Phase 1: mask rows [ms, ms+7] into LDS; 4 pixels/thread -------
    {
        const int col4 = (tid & 31) * 4;       // 0,4,...,124
        const int r    = tid >> 5;             // 0..7 (one mask row/thread)
        int gr = ms + r; if (gr > IH - 1) gr = IH - 1;   // clamp (row unused)
        const int h = gy * IH + gr;
        const float rely = (iy - (float)(h * s + sh)) * inv_soi;

        const float* fbase = mf + (size_t)(im * 8) * HW + (size_t)h * WW
                             + gx * IW + col4;
        float4 f[8];
        #pragma unroll
        for (int c = 0; c < 8; ++c)
            f[c] = *(const float4*)(fbase + (size_t)c * HW);

        float4 res;
        float* rv = &res.x;
        #pragma unroll
        for (int j = 0; j < 4; ++j) {
            const float relx = (ix - (float)((gx * IW + col4 + j) * s + sh)) * inv_soi;
            // layer 0: 10 -> 8, relu
            float a[8];
            #pragma unroll
            for (int k = 0; k < 8; ++k) {
                float acc = p[152 + k];
                acc = fmaf(p[k * 10 + 0], relx, acc);
                acc = fmaf(p[k * 10 + 1], rely, acc);
                #pragma unroll
                for (int c = 0; c < 8; ++c)
                    acc = fmaf(p[k * 10 + 2 + c], ((const float*)&f[c])[j], acc);
                a[k] = fmaxf(acc, 0.0f);
            }
            // layer 1: 8 -> 8, relu
            float b[8];
            #pragma unroll
            for (int k = 0; k < 8; ++k) {
                float acc = p[160 + k];
                #pragma unroll
                for (int c = 0; c < 8; ++c)
                    acc = fmaf(p[80 + k * 8 + c], a[c], acc);
                b[k] = fmaxf(acc, 0.0f);
            }
            // layer 2: 8 -> 1
            float acc = p[168];
            #pragma unroll
            for (int c = 0; c < 8; ++c)
                acc = fmaf(p[144 + c], b[c], acc);
            rv[j] = acc;
        }
        *(float4*)&m[r * IW + col4] = res;
    }
    __syncthreads();

    // ------- Phase 2: one output column/thread, 12 rows, sigmoid ------------
    {
        const int ocol = tid;                                  // 0..255
        const float wpos = (float)ocol * (127.0f / 255.0f);
        int wlo = (int)wpos; if (wlo > IW - 2) wlo = IW - 2;
        const float fw = wpos - (float)wlo;

        float* op = out + (size_t)inst * HW + (size_t)orow0 * WW + ocol;

        #pragma unroll
        for (int r = 0; r < 12; ++r) {
            const float hpos = (float)(orow0 + r) * (95.0f / 191.0f);
            int hlo = (int)hpos; if (hlo > IH - 2) hlo = IH - 2;
            const float fh = hpos - (float)hlo;
            const int rl = hlo - ms;                           // 0..6 (uniform)

            const float* mp = &m[rl * IW + wlo];
            const float v00 = mp[0];
            const float v01 = mp[1];
            const float v10 = mp[IW];
            const float v11 = mp[IW + 1];

            const float top = fmaf(fw, v01 - v00, v00);
            const float bot = fmaf(fw, v11 - v10, v10);
            const float val = fmaf(fh, bot - top, top);

            op[(size_t)r * WW] = 1.0f / (1.0f + __expf(-val));
        }
    }
}

extern "C" void kernel_launch(void* const* d_in, const int* in_sizes, int n_in,
                              void* d_out, int out_size, void* d_ws, size_t ws_size,
                              hipStream_t stream) {
    const float* mf       = (const float*)d_in[0];
    const float* params   = (const float*)d_in[1];
    const float* locs     = (const float*)d_in[2];
    const int*   im_inds  = (const int*)d_in[3];
    const int*   fpn      = (const int*)d_in[4];
    const int*   stride_p = (const int*)d_in[5];
    float*       out      = (float*)d_out;

    dmh_kernel<<<dim3(2048), dim3(256), 0, stream>>>(
        mf, params, locs, im_inds, fpn, stride_p, out);
}